// Round 16
// baseline (117.287 us; speedup 1.0000x reference)
//
#include <hip/hip_runtime.h>
#include <hip/hip_bf16.h>

#define NB 4
#define NT 2048
#define NE 512
#define NH 8
#define ND 64
#define BH (NB*NH)

#define LOG2E 1.44269504088896340736f

typedef __attribute__((ext_vector_type(8))) short short8;
typedef __attribute__((ext_vector_type(4))) short short4v;
typedef __attribute__((ext_vector_type(4))) float f32x4;

typedef const __attribute__((address_space(3))) short* lds_sp;

__device__ __forceinline__ f32x4 mfma16(short8 a, short8 b, f32x4 c){
  return __builtin_amdgcn_mfma_f32_16x16x32_bf16(a, b, c, 0, 0, 0);
}
__device__ __forceinline__ short f2b(float f){
  union { float f; unsigned u; } v; v.f = f;
  unsigned r = v.u + 0x7FFFu + ((v.u >> 16) & 1u);
  return (short)(r >> 16);
}
__device__ __forceinline__ float b2f(short s){
  union { unsigned u; float f; } v; v.u = ((unsigned)(unsigned short)s) << 16; return v.f;
}
// packed f32x2 -> bf16x2 via compiler-mediated cvt (backend emits v_cvt_pk_bf16_f32, RNE)
__device__ __forceinline__ unsigned pk2(float a, float b){
  union { __hip_bfloat162 h; unsigned u; } v;
  v.h = __float22bfloat162_rn(make_float2(a, b));
  return v.u;
}
// fast 2^x: compiler intrinsic (hazard-managed v_exp_f32), NOT inline asm, NOT libcall
__device__ __forceinline__ float fexp2(float x){
#if __has_builtin(__builtin_amdgcn_exp2f)
  return __builtin_amdgcn_exp2f(x);
#else
  return __expf(0.69314718055994530942f * x);
#endif
}
__device__ __forceinline__ void gld16(const void* g, void* l){
  __builtin_amdgcn_global_load_lds((const __attribute__((address_space(1))) void*)g,
                                   (__attribute__((address_space(3))) void*)l, 16, 0, 0);
}
__device__ __forceinline__ short4v trr(lds_sp p, int imm){
  short4v r;
  asm volatile("ds_read_b64_tr_b16 %0, %1 offset:%2" : "=v"(r) : "v"(p), "i"(imm));
  return r;
}

// ---------------- pack x (fp32 -> bf16) ----------------
__global__ __launch_bounds__(256) void pack_x_k(const float* __restrict__ x, short* __restrict__ xb){
  int i = blockIdx.x*256 + threadIdx.x;
  f32x4 a = ((const f32x4*)x)[2*i];
  f32x4 b = ((const f32x4*)x)[2*i+1];
  union { short8 s; unsigned u[4]; } o;
  o.u[0] = pk2(a[0], a[1]);
  o.u[1] = pk2(a[2], a[3]);
  o.u[2] = pk2(b[0], b[1]);
  o.u[3] = pk2(b[2], b[3]);
  ((short8*)xb)[i] = o.s;
}

// ---------------- pack W transposed (fp32 [e][j] -> bf16 [j][e]) ----------------
__global__ __launch_bounds__(256) void pack_wt_k(const float* __restrict__ Wq, const float* __restrict__ Wk,
                                                 const float* __restrict__ Wv, const float* __restrict__ Wo,
                                                 short* __restrict__ Wt){
  const float* W = blockIdx.z==0?Wq: blockIdx.z==1?Wk: blockIdx.z==2?Wv:Wo;
  short* out = Wt + (size_t)blockIdx.z*NE*NE;
  __shared__ float t[32][33];
  int tx = threadIdx.x & 31, ty = threadIdx.x >> 5;
  int j0 = blockIdx.x*32, e0 = blockIdx.y*32;
#pragma unroll
  for (int r = 0; r < 4; ++r)
    t[ty*4+r][tx] = W[(size_t)(e0+ty*4+r)*NE + j0+tx];
  __syncthreads();
#pragma unroll
  for (int r = 0; r < 4; ++r)
    out[(size_t)(j0+ty*4+r)*NE + e0+tx] = f2b(t[tx][ty*4+r]);
}

// ---------------- QKV projection GEMM: BK=32, S0/S1 double-buffered prefetch (proven attn pattern) ----------------
__global__ __launch_bounds__(256) void gemm_qkv_k(const short* __restrict__ xb, const short* __restrict__ Wt,
                                                  const float* __restrict__ bq, const float* __restrict__ bk,
                                                  const float* __restrict__ bv,
                                                  short* __restrict__ Q, short* __restrict__ K, short* __restrict__ V){
  int z = blockIdx.z;
  const short* Bm = Wt + (size_t)z*NE*NE;
  const float* bias = z==0?bq: z==1?bk:bv;
  short* out = z==0?Q: z==1?K:V;
  // fold 1/sqrt(D) AND log2(e) into Q: attention uses fexp2 directly
  float scale = (z==0) ? 0.125f*LOG2E : 1.0f;

  __shared__ short A0[128*32], B0[128*32];
  __shared__ short A1[128*32], B1[128*32];
  int tid = threadIdx.x, lane = tid & 63, wid = tid >> 6;
  int m0 = blockIdx.y*128, n0 = blockIdx.x*128;
  int wm = wid >> 1, wn = wid & 1;
  int sr = lane >> 2, sg = lane & 3;
  int fr = lane & 15, fg = lane >> 4;

  f32x4 acc[4][4] = {};

  auto stageG = [&](short* Ad, short* Bd, int kt){
    int k0 = kt*32;
    int ii0 = wid*2, ii1 = wid*2+1;
    int r0 = ii0*16 + sr, r1 = ii1*16 + sr;
    gld16(xb + (size_t)(m0 + r0)*NE + k0 + ((sg ^ (r0&3))<<3), Ad + ii0*512);
    gld16(xb + (size_t)(m0 + r1)*NE + k0 + ((sg ^ (r1&3))<<3), Ad + ii1*512);
    gld16(Bm + (size_t)(n0 + r0)*NE + k0 + ((sg ^ (r0&3))<<3), Bd + ii0*512);
    gld16(Bm + (size_t)(n0 + r1)*NE + k0 + ((sg ^ (r1&3))<<3), Bd + ii1*512);
  };
  auto computeG = [&](const short* As, const short* Bs){
    short8 af[4], bf[4];
#pragma unroll
    for (int m = 0; m < 4; ++m){
      int row = wm*64 + m*16 + fr;
      af[m] = *(const short8*)&As[row*32 + ((fg ^ (row&3))<<3)];
    }
#pragma unroll
    for (int n = 0; n < 4; ++n){
      int row = wn*64 + n*16 + fr;
      bf[n] = *(const short8*)&Bs[row*32 + ((fg ^ (row&3))<<3)];
    }
#pragma unroll
    for (int m = 0; m < 4; ++m)
#pragma unroll
      for (int n = 0; n < 4; ++n)
        acc[m][n] = mfma16(af[m], bf[n], acc[m][n]);
  };

  stageG(A0, B0, 0);
  __syncthreads();

  for (int kt2 = 0; kt2 < 8; ++kt2){
    int ktA = kt2*2;
    stageG(A1, B1, ktA+1);       // prefetch overlaps compute(A0/B0)
    computeG(A0, B0);
    __syncthreads();             // drains prefetch; all waves done with buf0
    if (ktA+2 < 16) stageG(A0, B0, ktA+2);
    computeG(A1, B1);
    __syncthreads();
  }

#pragma unroll
  for (int m = 0; m < 4; ++m)
#pragma unroll
    for (int n = 0; n < 4; ++n)
#pragma unroll
      for (int i = 0; i < 4; ++i){
        int row = m0 + wm*64 + m*16 + fg*4 + i;
        int col = n0 + wn*64 + n*16 + fr;
        float v = (acc[m][n][i] + bias[col]) * scale;
        int b = row >> 11, t = row & (NT-1), h = col >> 6, d = col & 63;
        out[(((size_t)(b*NH + h)*NT + t)<<6) + d] = f2b(v);
      }
}

// ---------------- pass 1: column sums + in-place V scaling (distinct dbuf objects Qs0/Qs1) ----------------
// Block owns k rows [kt*128, +128) of head bh — exactly the V rows its rl values scale.
__global__ __launch_bounds__(512, 4) void attn_l_k(const short* __restrict__ Q, const short* __restrict__ K,
                                                   const short* __restrict__ V, short* __restrict__ Vp){
  int bid = blockIdx.x;
  int bh = (bid & 7)*4 + ((bid >> 3) & 3);
  int kt = bid >> 5;                       // k-tile of 128 rows
  const short* Qh = Q + (size_t)bh*NT*ND;
  const short* Kh = K + (size_t)bh*NT*ND;
  __shared__ short Qs0[8192];              // distinct objects so ds_read(Qs0) never waits on gld16->Qs1
  __shared__ short Qs1[8192];
  __shared__ float rl_all[128];
  int tid = threadIdx.x, lane = tid&63, wid = tid>>6;
  int fr = lane&15, fg = lane>>4;
  int sr = lane>>3, sg = lane&7;

  // K fragments hoisted: wave owns k rows [kt*128 + wid*16, +16)
  int krow = kt*128 + wid*16;
  short8 ak[2];
#pragma unroll
  for (int dh = 0; dh < 2; ++dh)
    ak[dh] = *(const short8*)&Kh[(size_t)(krow + fr)*ND + dh*32 + fg*8];

  const short* qsrc0 = Qh + (size_t)(wid*16 + sr)*ND + ((sg ^ sr)<<3);
  const short* qsrc1 = qsrc0 + 8*ND;
  auto stageQ = [&](short* qb, int t){
    size_t adv = (size_t)t*128*ND;
    gld16(qsrc0 + adv, qb + wid*1024);
    gld16(qsrc1 + adv, qb + wid*1024 + 512);
  };

  float rs[4] = {0.f,0.f,0.f,0.f};

  auto computeQ = [&](const short* Qt){
#pragma unroll
    for (int qf = 0; qf < 8; ++qf){
      int row = qf*16 + fr;
      short8 b0 = *(const short8*)&Qt[row*64 + ((fg ^ (row&7))<<3)];
      short8 b1 = *(const short8*)&Qt[row*64 + (((4+fg) ^ (row&7))<<3)];
      f32x4 c = {};
      c = mfma16(ak[0], b0, c);
      c = mfma16(ak[1], b1, c);
#pragma unroll
      for (int i = 0; i < 4; ++i)
        rs[i] += fexp2(c[i]);
    }
  };

  stageQ(Qs0, 0);
  __syncthreads();

  for (int qt2 = 0; qt2 < 8; ++qt2){
    int qtA = qt2*2;
    stageQ(Qs1, qtA+1);          // qtA+1 <= 15
    computeQ(Qs0);
    __syncthreads();             // drains stage->Qs1; all waves done with Qs0
    if (qtA+2 < 16) stageQ(Qs0, qtA+2);
    computeQ(Qs1);
    __syncthreads();
  }

  // reduce over q; wave-local LDS broadcast of its 16 reciprocals
#pragma unroll
  for (int i = 0; i < 4; ++i){
    float v = rs[i];
    v += __shfl_xor(v, 1); v += __shfl_xor(v, 2);
    v += __shfl_xor(v, 4); v += __shfl_xor(v, 8);
    if (fr == 0) rl_all[wid*16 + fg*4 + i] = 1.0f / v;
  }
  // scale own 16 V rows (wave w handles rows [16w,16w+16) = its own rl values; no barrier needed)
  {
    int row = tid >> 2;                 // [16*wid, 16*wid+16)
    int col0 = (tid & 3) * 16;
    float inv = rl_all[row];
    const short* vsrc = V  + (size_t)bh*NT*ND + (size_t)(kt*128 + row)*ND + col0;
    short*       vdst = Vp + (size_t)bh*NT*ND + (size_t)(kt*128 + row)*ND + col0;
    short8 v0 = *(const short8*)vsrc;
    short8 v1 = *(const short8*)(vsrc + 8);
    union { short8 s; unsigned u[4]; } o0, o1;
#pragma unroll
    for (int j = 0; j < 4; ++j){
      o0.u[j] = pk2(b2f(v0[2*j])*inv, b2f(v0[2*j+1])*inv);
      o1.u[j] = pk2(b2f(v1[2*j])*inv, b2f(v1[2*j+1])*inv);
    }
    *(short8*)vdst       = o0.s;
    *(short8*)(vdst + 8) = o1.s;
  }
}

// ---------------- pass 2: 2-phase pipeline with distinct double-buffer objects S0/S1 ----------------
// 256 threads (4 waves), q-tile 128 (wave owns 32 q). Per buffer: [0..4095]=K 64x64 XOR-swizzled,
// [4096..8191]=V in [16][16] row-major subtiles for ds_read_b64_tr_b16 (pi-permuted PV).
__global__ __launch_bounds__(256, 3) void attn_out_k(const short* __restrict__ Q, const short* __restrict__ K,
                                                     const short* __restrict__ Vp,
                                                     short* __restrict__ out2){
  int bid = blockIdx.x;
  int xcd = bid & 7, w = bid >> 3;          // XCD-swizzle: 4 heads per XCD
  int bh = xcd*4 + (w & 3);
  int q0 = (w >> 2) * 128;                  // q-tile of 128 rows
  int b = bh >> 3, h = bh & 7;
  const short* Qh = Q + (size_t)bh*NT*ND;
  const short* Kh = K + (size_t)bh*NT*ND;
  const short* Vh = Vp + (size_t)bh*NT*ND;
  __shared__ short S0[8192];
  __shared__ short S1[8192];
  int tid = threadIdx.x, lane = tid&63, wid = tid>>6;
  int fr = lane&15, fg = lane>>4;
  int sr = lane>>3, sg = lane&7;
  int qw = q0 + wid*32;

  // Q fragments hoisted (B-operand of swapped QK^T), 2 q-frags per wave
  short8 qreg[2][2];
#pragma unroll
  for (int qf = 0; qf < 2; ++qf)
#pragma unroll
    for (int dh = 0; dh < 2; ++dh)
      qreg[qf][dh] = *(const short8*)&Qh[(size_t)(qw + qf*16 + fr)*ND + dh*32 + fg*8];

  // staging sources (per-lane, pre-swizzled); LDS dest is wave-uniform base + lane*16B
  const short* ksrc0 = Kh + (size_t)(wid*16 + sr)*ND + ((sg ^ sr)<<3);
  const short* ksrc1 = ksrc0 + 8*ND;
  int vt0 = wid*4 + (lane>>5);
  int vt1 = vt0 + 2;
  int vr = (lane&31)>>1, vc0 = (lane&1)*8;
  const short* vsrc0 = Vh + (size_t)((vt0>>2)*16 + vr)*ND + (vt0&3)*16 + vc0;
  const short* vsrc1 = Vh + (size_t)((vt1>>2)*16 + vr)*ND + (vt1&3)*16 + vc0;

  auto stage2 = [&](short* sb, int t){
    size_t adv = (size_t)t*64*ND;
    gld16(ksrc0 + adv, sb + wid*1024);
    gld16(ksrc1 + adv, sb + wid*1024 + 512);
    gld16(vsrc0 + adv, sb + 4096 + wid*1024);
    gld16(vsrc1 + adv, sb + 4096 + wid*1024 + 512);
  };

  f32x4 oacc[2][4] = {};

  auto compute = [&](const short* Ks, const short* Vs){
    // swapped QK^T from LDS K (swizzled) x register Q
    short8 ak[4][2];
#pragma unroll
    for (int rf = 0; rf < 4; ++rf){
      int row = rf*16 + fr;
#pragma unroll
      for (int dh = 0; dh < 2; ++dh)
        ak[rf][dh] = *(const short8*)&Ks[row*64 + (((dh*4+fg) ^ (row&7))<<3)];
    }
    // per-qf: S -> P = exp2(S') packed into pi-permuted PV A-fragments (1/l already in Vp)
    short8 pa[2][2];
#pragma unroll
    for (int qf = 0; qf < 2; ++qf){
      f32x4 s[4];
      __builtin_amdgcn_s_setprio(1);
#pragma unroll
      for (int rf = 0; rf < 4; ++rf){
        f32x4 c = {};
        c = mfma16(ak[rf][0], qreg[qf][0], c);
        c = mfma16(ak[rf][1], qreg[qf][1], c);
        s[rf] = c;
      }
      __builtin_amdgcn_s_setprio(0);
#pragma unroll
      for (int c = 0; c < 2; ++c){
        union { short8 s8; unsigned u[4]; } p;
        p.u[0] = pk2(fexp2(s[2*c  ][0]), fexp2(s[2*c  ][1]));
        p.u[1] = pk2(fexp2(s[2*c  ][2]), fexp2(s[2*c  ][3]));
        p.u[2] = pk2(fexp2(s[2*c+1][0]), fexp2(s[2*c+1][1]));
        p.u[3] = pk2(fexp2(s[2*c+1][2]), fexp2(s[2*c+1][3]));
        pa[qf][c] = p.s8;
      }
    }

    // PV via hardware transpose reads of V subtiles
    lds_sp vbase = (lds_sp)(Vs + lane*4);   // byte addr = base + lane*8
#pragma unroll
    for (int c = 0; c < 2; ++c){
      short4v t0[4], t1[4];
#pragma unroll
      for (int n = 0; n < 4; ++n){
        t0[n] = trr(vbase, ((2*c  )*4 + n)*512);
        t1[n] = trr(vbase, ((2*c+1)*4 + n)*512);
      }
      asm volatile("s_waitcnt lgkmcnt(0)");
      __builtin_amdgcn_sched_barrier(0);
      __builtin_amdgcn_s_setprio(1);
#pragma unroll
      for (int n = 0; n < 4; ++n){
        short8 vb = __builtin_shufflevector(t0[n], t1[n], 0,1,2,3,4,5,6,7);
#pragma unroll
        for (int qf = 0; qf < 2; ++qf)
          oacc[qf][n] = mfma16(pa[qf][c], vb, oacc[qf][n]);
      }
      __builtin_amdgcn_s_setprio(0);
    }
  };

  stage2(S0, 0);
  __syncthreads();

  for (int kt2 = 0; kt2 < 16; ++kt2){
    int ktA = kt2*2;
    stage2(S1, ktA+1);           // ktA+1 <= 31 always
    compute(S0, S0 + 4096);
    __syncthreads();             // drains stage->S1; all waves done reading S0
    if (ktA+2 < 32) stage2(S0, ktA+2);
    compute(S1, S1 + 4096);
    __syncthreads();
  }

  // scrambled reshape write: (B,H,T,D) -> (B, T', H*D), r=h*256+t/8, e=64*(t%8)+d
#pragma unroll
  for (int qf = 0; qf < 2; ++qf)
#pragma unroll
    for (int n = 0; n < 4; ++n)
#pragma unroll
      for (int i = 0; i < 4; ++i){
        int t = qw + qf*16 + fg*4 + i;
        int d = n*16 + fr;
        int r = h*256 + (t>>3);
        int e = ((t&7)<<6) + d;
        out2[((size_t)(b*NT + r)<<9) + e] = f2b(oacc[qf][n][i]);
      }
}

// ---------------- output projection: out2 @ Wo + bo -> fp32 (BK=32, double-buffered) ----------------
__global__ __launch_bounds__(256) void gemm_out_k(const short* __restrict__ A, const short* __restrict__ Bm,
                                                  const float* __restrict__ bo, float* __restrict__ out){
  __shared__ short A0[128*32], B0[128*32];
  __shared__ short A1[128*32], B1[128*32];
  int tid = threadIdx.x, lane = tid & 63, wid = tid >> 6;
  int m0 = blockIdx.y*128, n0 = blockIdx.x*128;
  int wm = wid >> 1, wn = wid & 1;
  int sr = lane >> 2, sg = lane & 3;
  int fr = lane & 15, fg = lane >> 4;

  f32x4 acc[4][4] = {};

  auto stageG = [&](short* Ad, short* Bd, int kt){
    int k0 = kt*32;
    int ii0 = wid*2, ii1 = wid*2+1;
    int r0 = ii0*16 + sr, r1 = ii1*16 + sr;
    gld16(A  + (size_t)(m0 + r0)*NE + k0 + ((sg ^ (r0&3))<<3), Ad + ii0*512);
    gld16(A  + (size_t)(m0 + r1)*NE + k0 + ((sg ^ (r1&3))<<3), Ad + ii1*512);
    gld16(Bm + (size_t)(n0 + r0)*NE + k0 + ((sg ^ (r0&3))<<3), Bd + ii0*512);
    gld16(Bm + (size_t)(n0 + r1)*NE + k0 + ((sg ^ (r1&3))<<3), Bd + ii1*512);
  };
  auto computeG = [&](const short* As, const short* Bs){
    short8 af[4], bf[4];
#pragma unroll
    for (int m = 0; m < 4; ++m){
      int row = wm*64 + m*16 + fr;
      af[m] = *(const short8*)&As[row*32 + ((fg ^ (row&3))<<3)];
    }
#pragma unroll
    for (int n = 0; n < 4; ++n){
      int row = wn*64 + n*16 + fr;
      bf[n] = *(const short8*)&Bs[row*32 + ((fg ^ (row&3))<<3)];
    }
#pragma unroll
    for (int m = 0; m < 4; ++m)
#pragma unroll
      for (int n = 0; n < 4; ++n)
        acc[m][n] = mfma16(af[m], bf[n], acc[m][n]);
  };

  stageG(A0, B0, 0);
  __syncthreads();

  for (int kt2 = 0; kt2 < 8; ++kt2){
    int ktA = kt2*2;
    stageG(A1, B1, ktA+1);
    computeG(A0, B0);
    __syncthreads();
    if (ktA+2 < 16) stageG(A0, B0, ktA+2);
    computeG(A1, B1);
    __syncthreads();
  }

#pragma unroll
  for (int m = 0; m < 4; ++m)
#pragma unroll
    for (int n = 0; n < 4; ++n)
#pragma unroll
      for (int i = 0; i < 4; ++i){
        int row = m0 + wm*64 + m*16 + fg*4 + i;
        int col = n0 + wn*64 + n*16 + fr;
        out[(size_t)row*NE + col] = acc[m][n][i] + bo[col];
      }
}

extern "C" void kernel_launch(void* const* d_in, const int* in_sizes, int n_in,
                              void* d_out, int out_size, void* d_ws, size_t ws_size,
                              hipStream_t stream){
  const float* x  = (const float*)d_in[0];
  const float* Wq = (const float*)d_in[1];
  const float* bq = (const float*)d_in[2];
  const float* Wk = (const float*)d_in[3];
  const float* bk = (const float*)d_in[4];
  const float* Wv = (const float*)d_in[5];
  const float* bv = (const float*)d_in[6];
  const float* Wo = (const float*)d_in[7];
  const float* bo = (const float*)d_in[8];
  float* out = (float*)d_out;

  char* ws = (char*)d_ws;
  size_t off = 0;
  auto alloc = [&](size_t bytes){ void* p = ws + off; off = (off + bytes + 255) & ~(size_t)255; return p; };
  short* xb    = (short*)alloc((size_t)NB*NT*NE*2);
  short* Wt    = (short*)alloc((size_t)4*NE*NE*2);
  short* Qb    = (short*)alloc((size_t)NB*NT*NE*2);
  short* Kb    = (short*)alloc((size_t)NB*NT*NE*2);
  short* Vb    = (short*)alloc((size_t)NB*NT*NE*2);
  short* Vp    = (short*)alloc((size_t)NB*NT*NE*2);
  short* out2  = (short*)alloc((size_t)NB*NT*NE*2);
  (void)ws_size; (void)in_sizes; (void)n_in; (void)out_size;

  pack_x_k<<<dim3((NB*NT*NE/8)/256), dim3(256), 0, stream>>>(x, xb);
  pack_wt_k<<<dim3(NE/32, NE/32, 4), dim3(256), 0, stream>>>(Wq, Wk, Wv, Wo, Wt);
  gemm_qkv_k<<<dim3(NE/128, (NB*NT)/128, 3), dim3(256), 0, stream>>>(xb, Wt, bq, bk, bv, Qb, Kb, Vb);
  attn_l_k<<<dim3((NT/128)*BH), dim3(512), 0, stream>>>(Qb, Kb, Vb, Vp);
  attn_out_k<<<dim3((NT/128)*BH), dim3(256), 0, stream>>>(Qb, Kb, Vp, out2);
  gemm_out_k<<<dim3(NE/128, (NB*NT)/128), dim3(256), 0, stream>>>(out2, Wt + (size_t)3*NE*NE, bo, out);
}

// Round 17
// 104.408 us; speedup vs baseline: 1.1234x; 1.1234x over previous
//
#include <hip/hip_runtime.h>
#include <hip/hip_bf16.h>

#define NB 4
#define NT 2048
#define NE 512
#define NH 8
#define ND 64
#define BH (NB*NH)

#define LOG2E 1.44269504088896340736f

typedef __attribute__((ext_vector_type(8))) short short8;
typedef __attribute__((ext_vector_type(4))) short short4v;
typedef __attribute__((ext_vector_type(4))) float f32x4;

typedef const __attribute__((address_space(3))) short* lds_sp;

__device__ __forceinline__ f32x4 mfma16(short8 a, short8 b, f32x4 c){
  return __builtin_amdgcn_mfma_f32_16x16x32_bf16(a, b, c, 0, 0, 0);
}
__device__ __forceinline__ short f2b(float f){
  union { float f; unsigned u; } v; v.f = f;
  unsigned r = v.u + 0x7FFFu + ((v.u >> 16) & 1u);
  return (short)(r >> 16);
}
__device__ __forceinline__ float b2f(short s){
  union { unsigned u; float f; } v; v.u = ((unsigned)(unsigned short)s) << 16; return v.f;
}
// packed f32x2 -> bf16x2 via compiler-mediated cvt (backend emits v_cvt_pk_bf16_f32, RNE)
__device__ __forceinline__ unsigned pk2(float a, float b){
  union { __hip_bfloat162 h; unsigned u; } v;
  v.h = __float22bfloat162_rn(make_float2(a, b));
  return v.u;
}
// fast 2^x: compiler intrinsic (hazard-managed v_exp_f32), NOT inline asm, NOT libcall
__device__ __forceinline__ float fexp2(float x){
#if __has_builtin(__builtin_amdgcn_exp2f)
  return __builtin_amdgcn_exp2f(x);
#else
  return __expf(0.69314718055994530942f * x);
#endif
}
__device__ __forceinline__ void gld16(const void* g, void* l){
  __builtin_amdgcn_global_load_lds((const __attribute__((address_space(1))) void*)g,
                                   (__attribute__((address_space(3))) void*)l, 16, 0, 0);
}
__device__ __forceinline__ short4v trr(lds_sp p, int imm){
  short4v r;
  asm volatile("ds_read_b64_tr_b16 %0, %1 offset:%2" : "=v"(r) : "v"(p), "i"(imm));
  return r;
}

// ---------------- fused pack: x (fp32->bf16) + W transposed (fp32 [e][j] -> bf16 [j][e]) ----------------
__global__ __launch_bounds__(256) void pack_all_k(const float* __restrict__ x, short* __restrict__ xb,
                                                  const float* __restrict__ Wq, const float* __restrict__ Wk,
                                                  const float* __restrict__ Wv, const float* __restrict__ Wo,
                                                  short* __restrict__ Wt){
  int bid = blockIdx.x;
  if (bid < 2048){
    int i = bid*256 + threadIdx.x;
    f32x4 a = ((const f32x4*)x)[2*i];
    f32x4 b = ((const f32x4*)x)[2*i+1];
    union { short8 s; unsigned u[4]; } o;
    o.u[0] = pk2(a[0], a[1]);
    o.u[1] = pk2(a[2], a[3]);
    o.u[2] = pk2(b[0], b[1]);
    o.u[3] = pk2(b[2], b[3]);
    ((short8*)xb)[i] = o.s;
  } else {
    int wb = bid - 2048;           // 0..1023
    int z = wb >> 8;               // 0..3
    int rem = wb & 255;
    int j0 = (rem & 15)*32, e0 = (rem >> 4)*32;
    const float* W = z==0?Wq: z==1?Wk: z==2?Wv:Wo;
    short* out = Wt + (size_t)z*NE*NE;
    __shared__ float t[32][33];
    int tx = threadIdx.x & 31, ty = threadIdx.x >> 5;
#pragma unroll
    for (int r = 0; r < 4; ++r)
      t[ty*4+r][tx] = W[(size_t)(e0+ty*4+r)*NE + j0+tx];
    __syncthreads();
#pragma unroll
    for (int r = 0; r < 4; ++r)
      out[(size_t)(j0+ty*4+r)*NE + e0+tx] = f2b(t[tx][ty*4+r]);
  }
}

// ---------------- QKV projection GEMM (BK=64 single-buffered — r15-proven; + XCD swizzle) ----------------
// grid 768 flat = 8 XCDs x 96. Same-A-panel blocks (4 n, 3 z) land on one XCD for L2 reuse.
__global__ __launch_bounds__(256) void gemm_qkv_k(const short* __restrict__ xb, const short* __restrict__ Wt,
                                                  const float* __restrict__ bq, const float* __restrict__ bk,
                                                  const float* __restrict__ bv,
                                                  short* __restrict__ Q, short* __restrict__ K, short* __restrict__ V){
  int bid = blockIdx.x;
  int xcd = bid & 7;
  int j = bid >> 3;               // 0..95
  int n0 = (j & 3) * 128;
  int p = xcd*24 + (j >> 2);      // 0..191 bijective
  int z = p >> 6;                 // 0..2
  int m0 = (p & 63) * 128;

  const short* Bm = Wt + (size_t)z*NE*NE;
  const float* bias = z==0?bq: z==1?bk:bv;
  short* out = z==0?Q: z==1?K:V;
  // fold 1/sqrt(D) AND log2(e) into Q: attention uses fexp2 directly
  float scale = (z==0) ? 0.125f*LOG2E : 1.0f;

  __shared__ short As[128*64];
  __shared__ short Bs[128*64];
  int tid = threadIdx.x, lane = tid & 63, wid = tid >> 6;
  int wm = wid >> 1, wn = wid & 1;
  int sr = lane >> 3, sg = lane & 7;   // 8 rows/instr, 8 chunks(8 shorts)/row, XOR-swizzled
  int fr = lane & 15, fg = lane >> 4;

  f32x4 acc[4][4] = {};

  for (int kt = 0; kt < 8; ++kt){
    int k0 = kt*64;
#pragma unroll
    for (int jj = 0; jj < 4; ++jj){
      int ii = wid*4 + jj;
      int r = ii*8 + sr;
      gld16(xb + (size_t)(m0 + r)*NE + k0 + ((sg ^ sr)<<3), (short*)As + ii*512);
      gld16(Bm + (size_t)(n0 + r)*NE + k0 + ((sg ^ sr)<<3), (short*)Bs + ii*512);
    }
    __syncthreads();
    short8 af[4][2], bf[4][2];
#pragma unroll
    for (int m = 0; m < 4; ++m){
      int row = wm*64 + m*16 + fr;
#pragma unroll
      for (int dh = 0; dh < 2; ++dh)
        af[m][dh] = *(const short8*)&As[row*64 + (((dh*4+fg) ^ (row&7))<<3)];
    }
#pragma unroll
    for (int n = 0; n < 4; ++n){
      int row = wn*64 + n*16 + fr;
#pragma unroll
      for (int dh = 0; dh < 2; ++dh)
        bf[n][dh] = *(const short8*)&Bs[row*64 + (((dh*4+fg) ^ (row&7))<<3)];
    }
#pragma unroll
    for (int m = 0; m < 4; ++m)
#pragma unroll
      for (int n = 0; n < 4; ++n){
        acc[m][n] = mfma16(af[m][0], bf[n][0], acc[m][n]);
        acc[m][n] = mfma16(af[m][1], bf[n][1], acc[m][n]);
      }
    __syncthreads();
  }
#pragma unroll
  for (int m = 0; m < 4; ++m)
#pragma unroll
    for (int n = 0; n < 4; ++n)
#pragma unroll
      for (int i = 0; i < 4; ++i){
        int row = m0 + wm*64 + m*16 + fg*4 + i;
        int col = n0 + wn*64 + n*16 + fr;
        float v = (acc[m][n][i] + bias[col]) * scale;
        int b = row >> 11, t = row & (NT-1), h = col >> 6, d = col & 63;
        out[(((size_t)(b*NH + h)*NT + t)<<6) + d] = f2b(v);
      }
}

// ---------------- pass 1: column sums + in-place V scaling (distinct dbuf objects Qs0/Qs1) ----------------
// Block owns k rows [kt*128, +128) of head bh — exactly the V rows its rl values scale.
__global__ __launch_bounds__(512, 4) void attn_l_k(const short* __restrict__ Q, const short* __restrict__ K,
                                                   const short* __restrict__ V, short* __restrict__ Vp){
  int bid = blockIdx.x;
  int bh = (bid & 7)*4 + ((bid >> 3) & 3);
  int kt = bid >> 5;                       // k-tile of 128 rows
  const short* Qh = Q + (size_t)bh*NT*ND;
  const short* Kh = K + (size_t)bh*NT*ND;
  __shared__ short Qs0[8192];              // distinct objects so ds_read(Qs0) never waits on gld16->Qs1
  __shared__ short Qs1[8192];
  __shared__ float rl_all[128];
  int tid = threadIdx.x, lane = tid&63, wid = tid>>6;
  int fr = lane&15, fg = lane>>4;
  int sr = lane>>3, sg = lane&7;

  // K fragments hoisted: wave owns k rows [kt*128 + wid*16, +16)
  int krow = kt*128 + wid*16;
  short8 ak[2];
#pragma unroll
  for (int dh = 0; dh < 2; ++dh)
    ak[dh] = *(const short8*)&Kh[(size_t)(krow + fr)*ND + dh*32 + fg*8];

  const short* qsrc0 = Qh + (size_t)(wid*16 + sr)*ND + ((sg ^ sr)<<3);
  const short* qsrc1 = qsrc0 + 8*ND;
  auto stageQ = [&](short* qb, int t){
    size_t adv = (size_t)t*128*ND;
    gld16(qsrc0 + adv, qb + wid*1024);
    gld16(qsrc1 + adv, qb + wid*1024 + 512);
  };

  float rs[4] = {0.f,0.f,0.f,0.f};

  auto computeQ = [&](const short* Qt){
#pragma unroll
    for (int qf = 0; qf < 8; ++qf){
      int row = qf*16 + fr;
      short8 b0 = *(const short8*)&Qt[row*64 + ((fg ^ (row&7))<<3)];
      short8 b1 = *(const short8*)&Qt[row*64 + (((4+fg) ^ (row&7))<<3)];
      f32x4 c = {};
      c = mfma16(ak[0], b0, c);
      c = mfma16(ak[1], b1, c);
#pragma unroll
      for (int i = 0; i < 4; ++i)
        rs[i] += fexp2(c[i]);
    }
  };

  stageQ(Qs0, 0);
  __syncthreads();

  for (int qt2 = 0; qt2 < 8; ++qt2){
    int qtA = qt2*2;
    stageQ(Qs1, qtA+1);          // qtA+1 <= 15
    computeQ(Qs0);
    __syncthreads();             // drains stage->Qs1; all waves done with Qs0
    if (qtA+2 < 16) stageQ(Qs0, qtA+2);
    computeQ(Qs1);
    __syncthreads();
  }

  // reduce over q; wave-local LDS broadcast of its 16 reciprocals
#pragma unroll
  for (int i = 0; i < 4; ++i){
    float v = rs[i];
    v += __shfl_xor(v, 1); v += __shfl_xor(v, 2);
    v += __shfl_xor(v, 4); v += __shfl_xor(v, 8);
    if (fr == 0) rl_all[wid*16 + fg*4 + i] = 1.0f / v;
  }
  // scale own 16 V rows (wave w handles rows [16w,16w+16) = its own rl values; no barrier needed)
  {
    int row = tid >> 2;                 // [16*wid, 16*wid+16)
    int col0 = (tid & 3) * 16;
    float inv = rl_all[row];
    const short* vsrc = V  + (size_t)bh*NT*ND + (size_t)(kt*128 + row)*ND + col0;
    short*       vdst = Vp + (size_t)bh*NT*ND + (size_t)(kt*128 + row)*ND + col0;
    short8 v0 = *(const short8*)vsrc;
    short8 v1 = *(const short8*)(vsrc + 8);
    union { short8 s; unsigned u[4]; } o0, o1;
#pragma unroll
    for (int j = 0; j < 4; ++j){
      o0.u[j] = pk2(b2f(v0[2*j])*inv, b2f(v0[2*j+1])*inv);
      o1.u[j] = pk2(b2f(v1[2*j])*inv, b2f(v1[2*j+1])*inv);
    }
    *(short8*)vdst       = o0.s;
    *(short8*)(vdst + 8) = o1.s;
  }
}

// ---------------- pass 2: 2-phase pipeline with distinct double-buffer objects S0/S1 ----------------
// 256 threads (4 waves), q-tile 128 (wave owns 32 q). Per buffer: [0..4095]=K 64x64 XOR-swizzled,
// [4096..8191]=V in [16][16] row-major subtiles for ds_read_b64_tr_b16 (pi-permuted PV).
__global__ __launch_bounds__(256, 3) void attn_out_k(const short* __restrict__ Q, const short* __restrict__ K,
                                                     const short* __restrict__ Vp,
                                                     short* __restrict__ out2){
  int bid = blockIdx.x;
  int xcd = bid & 7, w = bid >> 3;          // XCD-swizzle: 4 heads per XCD
  int bh = xcd*4 + (w & 3);
  int q0 = (w >> 2) * 128;                  // q-tile of 128 rows
  int b = bh >> 3, h = bh & 7;
  const short* Qh = Q + (size_t)bh*NT*ND;
  const short* Kh = K + (size_t)bh*NT*ND;
  const short* Vh = Vp + (size_t)bh*NT*ND;
  __shared__ short S0[8192];
  __shared__ short S1[8192];
  int tid = threadIdx.x, lane = tid&63, wid = tid>>6;
  int fr = lane&15, fg = lane>>4;
  int sr = lane>>3, sg = lane&7;
  int qw = q0 + wid*32;

  // Q fragments hoisted (B-operand of swapped QK^T), 2 q-frags per wave
  short8 qreg[2][2];
#pragma unroll
  for (int qf = 0; qf < 2; ++qf)
#pragma unroll
    for (int dh = 0; dh < 2; ++dh)
      qreg[qf][dh] = *(const short8*)&Qh[(size_t)(qw + qf*16 + fr)*ND + dh*32 + fg*8];

  // staging sources (per-lane, pre-swizzled); LDS dest is wave-uniform base + lane*16B
  const short* ksrc0 = Kh + (size_t)(wid*16 + sr)*ND + ((sg ^ sr)<<3);
  const short* ksrc1 = ksrc0 + 8*ND;
  int vt0 = wid*4 + (lane>>5);
  int vt1 = vt0 + 2;
  int vr = (lane&31)>>1, vc0 = (lane&1)*8;
  const short* vsrc0 = Vh + (size_t)((vt0>>2)*16 + vr)*ND + (vt0&3)*16 + vc0;
  const short* vsrc1 = Vh + (size_t)((vt1>>2)*16 + vr)*ND + (vt1&3)*16 + vc0;

  auto stage2 = [&](short* sb, int t){
    size_t adv = (size_t)t*64*ND;
    gld16(ksrc0 + adv, sb + wid*1024);
    gld16(ksrc1 + adv, sb + wid*1024 + 512);
    gld16(vsrc0 + adv, sb + 4096 + wid*1024);
    gld16(vsrc1 + adv, sb + 4096 + wid*1024 + 512);
  };

  f32x4 oacc[2][4] = {};

  auto compute = [&](const short* Ks, const short* Vs){
    // swapped QK^T from LDS K (swizzled) x register Q
    short8 ak[4][2];
#pragma unroll
    for (int rf = 0; rf < 4; ++rf){
      int row = rf*16 + fr;
#pragma unroll
      for (int dh = 0; dh < 2; ++dh)
        ak[rf][dh] = *(const short8*)&Ks[row*64 + (((dh*4+fg) ^ (row&7))<<3)];
    }
    // per-qf: S -> P = exp2(S') packed into pi-permuted PV A-fragments (1/l already in Vp)
    short8 pa[2][2];
#pragma unroll
    for (int qf = 0; qf < 2; ++qf){
      f32x4 s[4];
      __builtin_amdgcn_s_setprio(1);
#pragma unroll
      for (int rf = 0; rf < 4; ++rf){
        f32x4 c = {};
        c = mfma16(ak[rf][0], qreg[qf][0], c);
        c = mfma16(ak[rf][1], qreg[qf][1], c);
        s[rf] = c;
      }
      __builtin_amdgcn_s_setprio(0);
#pragma unroll
      for (int c = 0; c < 2; ++c){
        union { short8 s8; unsigned u[4]; } p;
        p.u[0] = pk2(fexp2(s[2*c  ][0]), fexp2(s[2*c  ][1]));
        p.u[1] = pk2(fexp2(s[2*c  ][2]), fexp2(s[2*c  ][3]));
        p.u[2] = pk2(fexp2(s[2*c+1][0]), fexp2(s[2*c+1][1]));
        p.u[3] = pk2(fexp2(s[2*c+1][2]), fexp2(s[2*c+1][3]));
        pa[qf][c] = p.s8;
      }
    }

    // PV via hardware transpose reads of V subtiles
    lds_sp vbase = (lds_sp)(Vs + lane*4);   // byte addr = base + lane*8
#pragma unroll
    for (int c = 0; c < 2; ++c){
      short4v t0[4], t1[4];
#pragma unroll
      for (int n = 0; n < 4; ++n){
        t0[n] = trr(vbase, ((2*c  )*4 + n)*512);
        t1[n] = trr(vbase, ((2*c+1)*4 + n)*512);
      }
      asm volatile("s_waitcnt lgkmcnt(0)");
      __builtin_amdgcn_sched_barrier(0);
      __builtin_amdgcn_s_setprio(1);
#pragma unroll
      for (int n = 0; n < 4; ++n){
        short8 vb = __builtin_shufflevector(t0[n], t1[n], 0,1,2,3,4,5,6,7);
#pragma unroll
        for (int qf = 0; qf < 2; ++qf)
          oacc[qf][n] = mfma16(pa[qf][c], vb, oacc[qf][n]);
      }
      __builtin_amdgcn_s_setprio(0);
    }
  };

  stage2(S0, 0);
  __syncthreads();

  for (int kt2 = 0; kt2 < 16; ++kt2){
    int ktA = kt2*2;
    stage2(S1, ktA+1);           // ktA+1 <= 31 always
    compute(S0, S0 + 4096);
    __syncthreads();             // drains stage->S1; all waves done reading S0
    if (ktA+2 < 32) stage2(S0, ktA+2);
    compute(S1, S1 + 4096);
    __syncthreads();
  }

  // scrambled reshape write: (B,H,T,D) -> (B, T', H*D), r=h*256+t/8, e=64*(t%8)+d
#pragma unroll
  for (int qf = 0; qf < 2; ++qf)
#pragma unroll
    for (int n = 0; n < 4; ++n)
#pragma unroll
      for (int i = 0; i < 4; ++i){
        int t = qw + qf*16 + fg*4 + i;
        int d = n*16 + fr;
        int r = h*256 + (t>>3);
        int e = ((t&7)<<6) + d;
        out2[((size_t)(b*NT + r)<<9) + e] = f2b(oacc[qf][n][i]);
      }
}

// ---------------- output projection: out2 @ Wo + bo -> fp32 (BK=64 single-buffered + XCD swizzle) ----------------
// grid 256 flat = 8 XCDs x 32; same-A-panel blocks (4 n) on one XCD.
__global__ __launch_bounds__(256) void gemm_out_k(const short* __restrict__ A, const short* __restrict__ Bm,
                                                  const float* __restrict__ bo, float* __restrict__ out){
  int bid = blockIdx.x;
  int xcd = bid & 7;
  int j = bid >> 3;               // 0..31
  int n0 = (j & 3) * 128;
  int m0 = (xcd*8 + (j >> 2)) * 128;   // 0..63 bijective

  __shared__ short As[128*64];
  __shared__ short Bs[128*64];
  int tid = threadIdx.x, lane = tid & 63, wid = tid >> 6;
  int wm = wid >> 1, wn = wid & 1;
  int sr = lane >> 3, sg = lane & 7;
  int fr = lane & 15, fg = lane >> 4;

  f32x4 acc[4][4] = {};

  for (int kt = 0; kt < 8; ++kt){
    int k0 = kt*64;
#pragma unroll
    for (int jj = 0; jj < 4; ++jj){
      int ii = wid*4 + jj;
      int r = ii*8 + sr;
      gld16(A  + (size_t)(m0 + r)*NE + k0 + ((sg ^ sr)<<3), (short*)As + ii*512);
      gld16(Bm + (size_t)(n0 + r)*NE + k0 + ((sg ^ sr)<<3), (short*)Bs + ii*512);
    }
    __syncthreads();
    short8 af[4][2], bf[4][2];
#pragma unroll
    for (int m = 0; m < 4; ++m){
      int row = wm*64 + m*16 + fr;
#pragma unroll
      for (int dh = 0; dh < 2; ++dh)
        af[m][dh] = *(const short8*)&As[row*64 + (((dh*4+fg) ^ (row&7))<<3)];
    }
#pragma unroll
    for (int n = 0; n < 4; ++n){
      int row = wn*64 + n*16 + fr;
#pragma unroll
      for (int dh = 0; dh < 2; ++dh)
        bf[n][dh] = *(const short8*)&Bs[row*64 + (((dh*4+fg) ^ (row&7))<<3)];
    }
#pragma unroll
    for (int m = 0; m < 4; ++m)
#pragma unroll
      for (int n = 0; n < 4; ++n){
        acc[m][n] = mfma16(af[m][0], bf[n][0], acc[m][n]);
        acc[m][n] = mfma16(af[m][1], bf[n][1], acc[m][n]);
      }
    __syncthreads();
  }
#pragma unroll
  for (int m = 0; m < 4; ++m)
#pragma unroll
    for (int n = 0; n < 4; ++n)
#pragma unroll
      for (int i = 0; i < 4; ++i){
        int row = m0 + wm*64 + m*16 + fg*4 + i;
        int col = n0 + wn*64 + n*16 + fr;
        out[(size_t)row*NE + col] = acc[m][n][i] + bo[col];
      }
}

extern "C" void kernel_launch(void* const* d_in, const int* in_sizes, int n_in,
                              void* d_out, int out_size, void* d_ws, size_t ws_size,
                              hipStream_t stream){
  const float* x  = (const float*)d_in[0];
  const float* Wq = (const float*)d_in[1];
  const float* bq = (const float*)d_in[2];
  const float* Wk = (const float*)d_in[3];
  const float* bk = (const float*)d_in[4];
  const float* Wv = (const float*)d_in[5];
  const float* bv = (const float*)d_in[6];
  const float* Wo = (const float*)d_in[7];
  const float* bo = (const float*)d_in[8];
  float* out = (float*)d_out;

  char* ws = (char*)d_ws;
  size_t off = 0;
  auto alloc = [&](size_t bytes){ void* p = ws + off; off = (off + bytes + 255) & ~(size_t)255; return p; };
  short* xb    = (short*)alloc((size_t)NB*NT*NE*2);
  short* Wt    = (short*)alloc((size_t)4*NE*NE*2);
  short* Qb    = (short*)alloc((size_t)NB*NT*NE*2);
  short* Kb    = (short*)alloc((size_t)NB*NT*NE*2);
  short* Vb    = (short*)alloc((size_t)NB*NT*NE*2);
  short* Vp    = (short*)alloc((size_t)NB*NT*NE*2);
  short* out2  = (short*)alloc((size_t)NB*NT*NE*2);
  (void)ws_size; (void)in_sizes; (void)n_in; (void)out_size;

  pack_all_k<<<dim3(2048 + 1024), dim3(256), 0, stream>>>(x, xb, Wq, Wk, Wv, Wo, Wt);
  gemm_qkv_k<<<dim3(768), dim3(256), 0, stream>>>(xb, Wt, bq, bk, bv, Qb, Kb, Vb);
  attn_l_k<<<dim3((NT/128)*BH), dim3(512), 0, stream>>>(Qb, Kb, Vb, Vp);
  attn_out_k<<<dim3((NT/128)*BH), dim3(256), 0, stream>>>(Qb, Kb, Vp, out2);
  gemm_out_k<<<dim3(256), dim3(256), 0, stream>>>(out2, Wt + (size_t)3*NE*NE, bo, out);
}